// Round 1
// baseline (11365.256 us; speedup 1.0000x reference)
//
#include <hip/hip_runtime.h>
#include <cstdint>

#define EPS 1e-5f

// ---------------------------------------------------------------------------
// Tiny GEMM for the k/v path: Y[b,co,kc] = relu(bn(sum_c W[co,c] * X[b,c,kc]))
// KC = 19, so one block (64 threads, 19 active) per (co, b).
// ---------------------------------------------------------------------------
__global__ __launch_bounds__(64) void small_gemm_kernel(
    const float* __restrict__ Wm, const float* __restrict__ X,
    const float* __restrict__ bn, float* __restrict__ Y,
    int CO, int CI, int KC) {
  int co = blockIdx.x;
  int b  = blockIdx.y;
  int kc = threadIdx.x;
  if (kc >= KC) return;
  const float* Xb = X + (size_t)b * CI * KC;
  float acc = 0.f;
  for (int c = 0; c < CI; ++c)
    acc += Wm[(size_t)co * CI + c] * Xb[(size_t)c * KC + kc];
  float s  = bn[co] * rsqrtf(bn[3 * CO + co] + EPS);
  float bs = bn[CO + co] - bn[2 * CO + co] * s;
  float y  = acc * s + bs;
  Y[((size_t)b * CO + co) * KC + kc] = fmaxf(y, 0.f);
}

// ---------------------------------------------------------------------------
// Tiled fp32 GEMM for 1x1 conv + BN + ReLU.
// C[b, m, n] = relu(bn(sum_k W[m,k] * X[b,k,n]))
// Tile 64(m) x 64(n) x 16(k); 256 threads; 4x4 per thread.
// ---------------------------------------------------------------------------
#define BM 64
#define BN 64
#define BK 16
__global__ __launch_bounds__(256) void gemm1x1_kernel(
    const float* __restrict__ Wm, const float* __restrict__ X,
    const float* __restrict__ bn, float* __restrict__ Y,
    int CO, int CI, int N) {
  int b  = blockIdx.z;
  int n0 = blockIdx.x * BN;
  int m0 = blockIdx.y * BM;
  const float* Xb = X + (size_t)b * CI * N;
  float*       Yb = Y + (size_t)b * CO * N;

  __shared__ __align__(16) float As[BK][BM + 4]; // [k][m], stride 68 (16B-aligned rows)
  __shared__ __align__(16) float Bs[BK][BN];     // [k][n]

  int t  = threadIdx.x;
  int ty = t >> 4, tx = t & 15;
  float acc[4][4] = {};

  for (int k0 = 0; k0 < CI; k0 += BK) {
#pragma unroll
    for (int l = 0; l < 4; ++l) {
      int idx = t + l * 256;
      int m = idx >> 4, kk = idx & 15;
      As[kk][m] = Wm[(size_t)(m0 + m) * CI + k0 + kk];
    }
#pragma unroll
    for (int l = 0; l < 4; ++l) {
      int idx = t + l * 256;
      int kk = idx >> 6, n = idx & 63;
      Bs[kk][n] = Xb[(size_t)(k0 + kk) * N + n0 + n];
    }
    __syncthreads();
#pragma unroll
    for (int kk = 0; kk < BK; ++kk) {
      const float4 av = *reinterpret_cast<const float4*>(&As[kk][ty * 4]);
      const float4 bv = *reinterpret_cast<const float4*>(&Bs[kk][tx * 4]);
      const float a[4] = {av.x, av.y, av.z, av.w};
      const float bb[4] = {bv.x, bv.y, bv.z, bv.w};
#pragma unroll
      for (int i = 0; i < 4; ++i)
#pragma unroll
        for (int j = 0; j < 4; ++j) acc[i][j] += a[i] * bb[j];
    }
    __syncthreads();
  }

#pragma unroll
  for (int i = 0; i < 4; ++i) {
    int m = m0 + ty * 4 + i;
    float s  = bn[m] * rsqrtf(bn[3 * CO + m] + EPS);
    float bs = bn[CO + m] - bn[2 * CO + m] * s;
#pragma unroll
    for (int j = 0; j < 4; ++j) {
      int n = n0 + tx * 4 + j;
      float y = acc[i][j] * s + bs;
      Yb[(size_t)m * N + n] = fmaxf(y, 0.f);
    }
  }
}

// ---------------------------------------------------------------------------
// Attention: one thread per pixel. k/v (256x19 each) staged in LDS.
// sim[p,kk] = sum_c q[c,p]*k[c,kk] * 1/16 ; softmax over kk ; ctx[c,p] = sum sim*v
// ---------------------------------------------------------------------------
__global__ __launch_bounds__(256) void attention_kernel(
    const float* __restrict__ Q, const float* __restrict__ Kp,
    const float* __restrict__ Vp, float* __restrict__ Ctx, int N) {
  int b   = blockIdx.y;
  int pix = blockIdx.x * 256 + threadIdx.x;
  __shared__ float ks[256][19];
  __shared__ float vs[256][19];
  for (int idx = threadIdx.x; idx < 256 * 19; idx += 256) {
    int c = idx / 19, kk = idx % 19;
    ks[c][kk] = Kp[((size_t)b * 256 + c) * 19 + kk];
    vs[c][kk] = Vp[((size_t)b * 256 + c) * 19 + kk];
  }
  __syncthreads();

  const float* Qb = Q + (size_t)b * 256 * N;
  float sim[19];
#pragma unroll
  for (int kk = 0; kk < 19; ++kk) sim[kk] = 0.f;
  for (int c = 0; c < 256; ++c) {
    float qv = Qb[(size_t)c * N + pix];
#pragma unroll
    for (int kk = 0; kk < 19; ++kk) sim[kk] += qv * ks[c][kk];
  }
  const float scale = 0.0625f;  // 256^-0.5
  float mx = -1e30f;
#pragma unroll
  for (int kk = 0; kk < 19; ++kk) { sim[kk] *= scale; mx = fmaxf(mx, sim[kk]); }
  float denom = 0.f;
#pragma unroll
  for (int kk = 0; kk < 19; ++kk) { sim[kk] = __expf(sim[kk] - mx); denom += sim[kk]; }
  float inv = 1.f / denom;
#pragma unroll
  for (int kk = 0; kk < 19; ++kk) sim[kk] *= inv;

  float* Cb = Ctx + (size_t)b * 256 * N;
  for (int c = 0; c < 256; ++c) {
    float o = 0.f;
#pragma unroll
    for (int kk = 0; kk < 19; ++kk) o += sim[kk] * vs[c][kk];
    Cb[(size_t)c * N + pix] = o;
  }
}

// ---------------------------------------------------------------------------
// Repack wbot (CO,1024,3,3) -> Wr (CO, 9, 1024): k-order = tap*1024 + ci
// ---------------------------------------------------------------------------
__global__ __launch_bounds__(256) void repack_wbot_kernel(
    const float* __restrict__ Wb, float* __restrict__ Wr) {
  int idx = blockIdx.x * 256 + threadIdx.x;
  if (idx >= 512 * 9216) return;
  int co  = idx / 9216;
  int r   = idx % 9216;
  int tap = r / 1024;
  int ci  = r % 1024;
  Wr[idx] = Wb[((size_t)co * 1024 + ci) * 9 + tap];
}

// ---------------------------------------------------------------------------
// 3x3 conv as implicit GEMM, SAME padding, input = concat(ctx_out, x) on the
// channel axis (handled implicitly). M=CO=512, N=H*W, K=9*1024.
// A = Wr (k-contiguous), B gathered from ctx_out/x with bounds checks.
// BN + ReLU epilogue. n-tiles of 64 never cross a row (64 | W=256).
// ---------------------------------------------------------------------------
__global__ __launch_bounds__(256) void conv3x3_kernel(
    const float* __restrict__ Wr, const float* __restrict__ Ctx,
    const float* __restrict__ Xin, const float* __restrict__ bn,
    float* __restrict__ Y, int H, int W) {
  const int CO = 512, K = 9216;
  int b  = blockIdx.z;
  int n0 = blockIdx.x * BN;
  int m0 = blockIdx.y * BM;
  int HW = H * W;
  int h  = n0 / W;
  int w0 = n0 % W;
  const float* C0 = Ctx + (size_t)b * 512 * HW;
  const float* X0 = Xin + (size_t)b * 512 * HW;

  __shared__ __align__(16) float As[BK][BM + 4];
  __shared__ __align__(16) float Bs[BK][BN];

  int t  = threadIdx.x;
  int ty = t >> 4, tx = t & 15;
  float acc[4][4] = {};

  for (int k0 = 0; k0 < K; k0 += BK) {
#pragma unroll
    for (int l = 0; l < 4; ++l) {
      int idx = t + l * 256;
      int m = idx >> 4, kk = idx & 15;
      As[kk][m] = Wr[(size_t)(m0 + m) * K + k0 + kk];
    }
    // a 16-wide k-tile stays inside one tap (16 | 1024)
    int tap = k0 >> 10;
    int dy = tap / 3 - 1, dx = tap % 3 - 1;
    int hh = h + dy;
    bool hok = (hh >= 0) && (hh < H);
    int cibase = k0 & 1023;
#pragma unroll
    for (int l = 0; l < 4; ++l) {
      int idx = t + l * 256;
      int kk = idx >> 6, n = idx & 63;
      int ci = cibase + kk;
      int ww = w0 + n + dx;
      float val = 0.f;
      if (hok && ww >= 0 && ww < W) {
        const float* chan = (ci < 512) ? (C0 + (size_t)ci * HW)
                                       : (X0 + (size_t)(ci - 512) * HW);
        val = chan[hh * W + ww];
      }
      Bs[kk][n] = val;
    }
    __syncthreads();
#pragma unroll
    for (int kk = 0; kk < BK; ++kk) {
      const float4 av = *reinterpret_cast<const float4*>(&As[kk][ty * 4]);
      const float4 bv = *reinterpret_cast<const float4*>(&Bs[kk][tx * 4]);
      const float a[4] = {av.x, av.y, av.z, av.w};
      const float bb[4] = {bv.x, bv.y, bv.z, bv.w};
#pragma unroll
      for (int i = 0; i < 4; ++i)
#pragma unroll
        for (int j = 0; j < 4; ++j) acc[i][j] += a[i] * bb[j];
    }
    __syncthreads();
  }

#pragma unroll
  for (int i = 0; i < 4; ++i) {
    int m = m0 + ty * 4 + i;
    float s  = bn[m] * rsqrtf(bn[3 * CO + m] + EPS);
    float bs = bn[CO + m] - bn[2 * CO + m] * s;
#pragma unroll
    for (int j = 0; j < 4; ++j) {
      int n = n0 + tx * 4 + j;
      float y = acc[i][j] * s + bs;
      Y[((size_t)b * CO + m) * (size_t)HW + n] = fmaxf(y, 0.f);
    }
  }
}

// ---------------------------------------------------------------------------
extern "C" void kernel_launch(void* const* d_in, const int* in_sizes, int n_in,
                              void* d_out, int out_size, void* d_ws, size_t ws_size,
                              hipStream_t stream) {
  const float* x     = (const float*)d_in[0];
  const float* proxy = (const float*)d_in[1];
  const float* wq1   = (const float*)d_in[2];
  const float* bnq1  = (const float*)d_in[3];
  const float* wq2   = (const float*)d_in[4];
  const float* bnq2  = (const float*)d_in[5];
  const float* wk1   = (const float*)d_in[6];
  const float* bnk1  = (const float*)d_in[7];
  const float* wk2   = (const float*)d_in[8];
  const float* bnk2  = (const float*)d_in[9];
  const float* wv    = (const float*)d_in[10];
  const float* bnv   = (const float*)d_in[11];
  const float* wout  = (const float*)d_in[12];
  const float* bnout = (const float*)d_in[13];
  const float* wbot  = (const float*)d_in[14];
  const float* bnbot = (const float*)d_in[15];
  float* out = (float*)d_out;

  const int B = 2, C = 512, H = 128, W = 256, CK = 256, KC = 19, CO = 512;
  const int N = H * W;  // 32768

  char* ws = (char*)d_ws;
  const size_t MiB = 1024 * 1024;
  float* q1buf = (float*)(ws);                  // 64 MiB, reused as ctx
  float* qbuf  = (float*)(ws + 64 * MiB);       // 64 MiB
  float* ctx   = q1buf;                         // overwrites q1 (dead)
  float* ctxo  = (float*)(ws + 64 * MiB);       // 128 MiB, overwrites q (dead)
  float* Wr    = (float*)(ws + 192 * MiB);      // 18 MiB
  float* k1    = (float*)(ws + 212 * MiB);      // 3 x 38912 B
  float* k2    = k1 + (size_t)B * CK * KC;
  float* vv    = k2 + (size_t)B * CK * KC;

  // weight repack for conv (independent of everything else)
  repack_wbot_kernel<<<(512 * 9216 + 255) / 256, 256, 0, stream>>>(wbot, Wr);

  // k/v path (tiny)
  small_gemm_kernel<<<dim3(CK, B), 64, 0, stream>>>(wk1, proxy, bnk1, k1, CK, C, KC);
  small_gemm_kernel<<<dim3(CK, B), 64, 0, stream>>>(wk2, k1, bnk2, k2, CK, CK, KC);
  small_gemm_kernel<<<dim3(CK, B), 64, 0, stream>>>(wv, proxy, bnv, vv, CK, C, KC);

  // q path: two 1x1 conv+BN+ReLU
  gemm1x1_kernel<<<dim3(N / BN, CK / BM, B), 256, 0, stream>>>(wq1, x, bnq1, q1buf, CK, C, N);
  gemm1x1_kernel<<<dim3(N / BN, CK / BM, B), 256, 0, stream>>>(wq2, q1buf, bnq2, qbuf, CK, CK, N);

  // attention
  attention_kernel<<<dim3(N / 256, B), 256, 0, stream>>>(qbuf, k2, vv, ctx, N);

  // output 1x1 conv+BN+ReLU
  gemm1x1_kernel<<<dim3(N / BN, C / BM, B), 256, 0, stream>>>(wout, ctx, bnout, ctxo, C, CK, N);

  // 3x3 conv on implicit concat(ctx_out, x) + BN + ReLU
  conv3x3_kernel<<<dim3(N / BN, CO / BM, B), 256, 0, stream>>>(Wr, ctxo, x, bnbot, out, H, W);
}

// Round 3
// 1995.560 us; speedup vs baseline: 5.6953x; 5.6953x over previous
//
#include <hip/hip_runtime.h>
#include <cstdint>

#define EPS 1e-5f
#define PADW 258          // W+2
#define PADROWS 33540     // (H+2)*(W+2) = 130*258
#define NPIX 32768        // H*W per batch

typedef __attribute__((ext_vector_type(8))) short bf16x8;
typedef __attribute__((ext_vector_type(4))) float f32x4;

__device__ __forceinline__ ushort f2bf(float f) {
  union { float f; uint32_t u; } v; v.f = f;
  uint32_t r = v.u + 0x7fffu + ((v.u >> 16) & 1u);  // round-to-nearest-even
  return (ushort)(r >> 16);
}
__device__ __forceinline__ float bf2f(ushort h) {
  union { uint32_t u; float f; } v; v.u = ((uint32_t)h) << 16;
  return v.f;
}
__device__ __forceinline__ void gload_lds16(const void* g, void* lds) {
  __builtin_amdgcn_global_load_lds((__attribute__((address_space(1))) void*)g,
                                   (__attribute__((address_space(3))) void*)lds,
                                   16, 0, 0);
}

// ---------------------------------------------------------------------------
// Unified MFMA GEMM: C[m][n] = relu(bn(sum_k A[m][k] * Brow[rowmap(n)][k]))
// A: bf16 [M][K] (K-contiguous). B: bf16 rows of pitchB elements.
// BMODE: 0 = plain rows (row = n), 1 = padded rows (row = p(n)), ci offset,
//        2 = conv: padded rows + 9-tap K (K = 9*1024, tap shifts row)
// OMODE: 0 = bf16 transposed out [n][m] pitchO, 1 = bf16 into padded cat
//        [p(n)][m] pitchO, 2 = fp32 standard [m][n]
// Tile 128x128, BK=32, 4 waves in 2x2 quadrants of 64x64, each wave 4x4 MFMA
// 16x16x32 tiles (m97 shape).
// ---------------------------------------------------------------------------
template <int BMODE, int OMODE>
__global__ __launch_bounds__(256) void mfma_gemm(
    const ushort* __restrict__ A, const ushort* __restrict__ B,
    const float* __restrict__ bn, void* __restrict__ OutV,
    int M, int K, int pitchB, int ciB, long strideB, int pitchO, long strideO) {
  const int lane = threadIdx.x & 63;
  const int wave = threadIdx.x >> 6;
  const int wm = (wave & 1) * 64;   // wave quadrant offset in m
  const int wn = (wave >> 1) * 64;  // wave quadrant offset in n
  const int m0 = blockIdx.y * 128;
  const int n0 = blockIdx.x * 128;
  const int z  = blockIdx.z;
  B += (size_t)z * strideB;

  const int h = n0 >> 8, w0 = n0 & 255;  // W = 256; 128-tile stays in one row
  long prowB;
  if (BMODE == 0) prowB = n0;
  else            prowB = (long)(h + 1) * PADW + (w0 + 1);

  __shared__ __align__(16) ushort Asl[4 * 128 * 8];  // [ks][m][8], 8 KB
  __shared__ __align__(16) ushort Bsl[4 * 128 * 8];  // [ks][n][8]

  f32x4 acc[4][4];
#pragma unroll
  for (int mt = 0; mt < 4; ++mt)
#pragma unroll
    for (int nt = 0; nt < 4; ++nt) acc[mt][nt] = (f32x4){0.f, 0.f, 0.f, 0.f};

  for (int k0 = 0; k0 < K; k0 += 32) {
    // ---- A staging: 8 KB, 8 x (64 lanes x 16B), 2 instrs per wave
#pragma unroll
    for (int i = 0; i < 2; ++i) {
      int s = wave * 2 + i;
      int c = s * 64 + lane;          // chunk = ks*128 + m
      int mm = c & 127, ks = c >> 7;
      gload_lds16(A + (size_t)(m0 + mm) * K + (k0 + ks * 8), Asl + s * 512);
    }
    // ---- B staging
    long rowb; int cib;
    if (BMODE == 2) {
      int tap = k0 >> 10;             // 32 | 1024 -> chunk within one tap
      int dy = tap / 3 - 1, dx = tap % 3 - 1;
      rowb = prowB + dy * PADW + dx;
      cib  = k0 & 1023;
    } else {
      rowb = prowB;
      cib  = ciB + k0;
    }
#pragma unroll
    for (int i = 0; i < 2; ++i) {
      int s = wave * 2 + i;
      int c = s * 64 + lane;
      int nn = c & 127, ks = c >> 7;
      gload_lds16(B + (size_t)(rowb + nn) * pitchB + cib + ks * 8, Bsl + s * 512);
    }
    __syncthreads();
    // ---- fragments: A[m=lane&15][k=(lane>>4)*8+j]; B symmetric on n
    bf16x8 af[4], bfr[4];
#pragma unroll
    for (int t = 0; t < 4; ++t) {
      af[t]  = *(const bf16x8*)(Asl + (((lane >> 4) * 128) + wm + t * 16 + (lane & 15)) * 8);
      bfr[t] = *(const bf16x8*)(Bsl + (((lane >> 4) * 128) + wn + t * 16 + (lane & 15)) * 8);
    }
#pragma unroll
    for (int mt = 0; mt < 4; ++mt)
#pragma unroll
      for (int nt = 0; nt < 4; ++nt)
        acc[mt][nt] = __builtin_amdgcn_mfma_f32_16x16x32_bf16(af[mt], bfr[nt], acc[mt][nt], 0, 0, 0);
    __syncthreads();
  }

  // ---- epilogue: BN + ReLU.  C/D layout: col=lane&15 (n), row=(lane>>4)*4+r (m)
  const int q4 = lane >> 4, col = lane & 15;
  float scv[16], bov[16];
#pragma unroll
  for (int mt = 0; mt < 4; ++mt)
#pragma unroll
    for (int r = 0; r < 4; ++r) {
      int m = m0 + wm + mt * 16 + q4 * 4 + r;
      float s = bn[m] * rsqrtf(bn[3 * M + m] + EPS);
      scv[mt * 4 + r] = s;
      bov[mt * 4 + r] = bn[M + m] - bn[2 * M + m] * s;
    }
  if (OMODE == 2) {
    float* Outf = (float*)OutV + (size_t)z * strideO;
#pragma unroll
    for (int mt = 0; mt < 4; ++mt)
#pragma unroll
      for (int r = 0; r < 4; ++r) {
        int m = m0 + wm + mt * 16 + q4 * 4 + r;
        float* rowp = Outf + (size_t)m * NPIX + n0 + wn;
#pragma unroll
        for (int nt = 0; nt < 4; ++nt)
          rowp[nt * 16 + col] = fmaxf(acc[mt][nt][r] * scv[mt * 4 + r] + bov[mt * 4 + r], 0.f);
      }
  } else {
    ushort* Outh = (ushort*)OutV + (size_t)z * strideO;
    long prowO = (OMODE == 0) ? (long)n0 : ((long)(h + 1) * PADW + (w0 + 1));
#pragma unroll
    for (int nt = 0; nt < 4; ++nt) {
      long row = prowO + wn + nt * 16 + col;
      ushort* p = Outh + (size_t)row * pitchO + m0 + wm;
#pragma unroll
      for (int mt = 0; mt < 4; ++mt) {
        ushort4 pk;
        pk.x = f2bf(fmaxf(acc[mt][nt][0] * scv[mt * 4 + 0] + bov[mt * 4 + 0], 0.f));
        pk.y = f2bf(fmaxf(acc[mt][nt][1] * scv[mt * 4 + 1] + bov[mt * 4 + 1], 0.f));
        pk.z = f2bf(fmaxf(acc[mt][nt][2] * scv[mt * 4 + 2] + bov[mt * 4 + 2], 0.f));
        pk.w = f2bf(fmaxf(acc[mt][nt][3] * scv[mt * 4 + 3] + bov[mt * 4 + 3], 0.f));
        *(ushort4*)(p + mt * 16 + q4 * 4) = pk;
      }
    }
  }
}

// ---------------------------------------------------------------------------
// Tiny GEMM for the k/v path (fp32, negligible cost)
// ---------------------------------------------------------------------------
__global__ __launch_bounds__(64) void small_gemm_kernel(
    const float* __restrict__ Wm, const float* __restrict__ X,
    const float* __restrict__ bn, float* __restrict__ Y,
    int CO, int CI, int KC) {
  int co = blockIdx.x, b = blockIdx.y, kc = threadIdx.x;
  if (kc >= KC) return;
  const float* Xb = X + (size_t)b * CI * KC;
  float acc = 0.f;
  for (int c = 0; c < CI; ++c) acc += Wm[(size_t)co * CI + c] * Xb[(size_t)c * KC + kc];
  float s  = bn[co] * rsqrtf(bn[3 * CO + co] + EPS);
  float bs = bn[CO + co] - bn[2 * CO + co] * s;
  Y[((size_t)b * CO + co) * KC + kc] = fmaxf(acc * s + bs, 0.f);
}

// ---------------------------------------------------------------------------
// Attention: qT/ctxT in [pixel][256ch] bf16; k/v fp32 staged in LDS.
// ---------------------------------------------------------------------------
__global__ __launch_bounds__(256) void attention_kernel(
    const ushort* __restrict__ qT, const float* __restrict__ Kp,
    const float* __restrict__ Vp, ushort* __restrict__ ctxT) {
  int b = blockIdx.y;
  int pix = blockIdx.x * 256 + threadIdx.x;
  __shared__ float ks[256][19], vs[256][19];
  for (int idx = threadIdx.x; idx < 256 * 19; idx += 256) {
    int c = idx / 19, kk = idx % 19;
    ks[c][kk] = Kp[((size_t)b * 256 + c) * 19 + kk];
    vs[c][kk] = Vp[((size_t)b * 256 + c) * 19 + kk];
  }
  __syncthreads();

  const ushort* qrow = qT + ((size_t)b * NPIX + pix) * 256;
  float sim[19];
#pragma unroll
  for (int kk = 0; kk < 19; ++kk) sim[kk] = 0.f;
  for (int c0 = 0; c0 < 256; c0 += 8) {
    uint4 raw = *(const uint4*)(qrow + c0);
    float qf[8] = {bf2f((ushort)(raw.x & 0xffff)), bf2f((ushort)(raw.x >> 16)),
                   bf2f((ushort)(raw.y & 0xffff)), bf2f((ushort)(raw.y >> 16)),
                   bf2f((ushort)(raw.z & 0xffff)), bf2f((ushort)(raw.z >> 16)),
                   bf2f((ushort)(raw.w & 0xffff)), bf2f((ushort)(raw.w >> 16))};
#pragma unroll
    for (int j = 0; j < 8; ++j)
#pragma unroll
      for (int kk = 0; kk < 19; ++kk) sim[kk] += qf[j] * ks[c0 + j][kk];
  }
  const float scale = 0.0625f;  // 256^-0.5
  float mx = -1e30f;
#pragma unroll
  for (int kk = 0; kk < 19; ++kk) { sim[kk] *= scale; mx = fmaxf(mx, sim[kk]); }
  float denom = 0.f;
#pragma unroll
  for (int kk = 0; kk < 19; ++kk) { sim[kk] = __expf(sim[kk] - mx); denom += sim[kk]; }
  float inv = 1.f / denom;
#pragma unroll
  for (int kk = 0; kk < 19; ++kk) sim[kk] *= inv;

  ushort* crow = ctxT + ((size_t)b * NPIX + pix) * 256;
  for (int c0 = 0; c0 < 256; c0 += 8) {
    uint32_t o[4];
#pragma unroll
    for (int j = 0; j < 4; ++j) {
      float v0 = 0.f, v1 = 0.f;
#pragma unroll
      for (int kk = 0; kk < 19; ++kk) {
        v0 += sim[kk] * vs[c0 + j * 2][kk];
        v1 += sim[kk] * vs[c0 + j * 2 + 1][kk];
      }
      o[j] = (uint32_t)f2bf(v0) | ((uint32_t)f2bf(v1) << 16);
    }
    *(uint4*)(crow + c0) = make_uint4(o[0], o[1], o[2], o[3]);
  }
}

// ---------------------------------------------------------------------------
// Transpose x (fp32 [b][512][HW]) into cat_pad (bf16 [b][p][1024], ch 512..1023)
// ---------------------------------------------------------------------------
__global__ __launch_bounds__(256) void transpose_x_kernel(
    const float* __restrict__ x, ushort* __restrict__ cat) {
  int b = blockIdx.z, ci0 = blockIdx.y * 64, n0 = blockIdx.x * 64;
  __shared__ float t[64][65];
  const float* xb = x + ((size_t)b * 512 + ci0) * NPIX + n0;
  for (int i = 0; i < 16; ++i) {
    int idx = i * 256 + threadIdx.x;
    int c = idx >> 6, w = idx & 63;
    t[c][w] = xb[(size_t)c * NPIX + w];
  }
  __syncthreads();
  int h = n0 >> 8, w0 = n0 & 255;
  size_t pbase = ((size_t)b * PADROWS + (size_t)(h + 1) * PADW + (w0 + 1)) * 1024 + 512 + ci0;
  for (int i = 0; i < 16; ++i) {
    int idx = i * 256 + threadIdx.x;
    int n = idx >> 6, c = idx & 63;
    cat[pbase + (size_t)n * 1024 + c] = f2bf(t[c][n]);
  }
}

// ---------------------------------------------------------------------------
// Weight conversions
// ---------------------------------------------------------------------------
__global__ void convert_w_kernel(const float* __restrict__ in, ushort* __restrict__ out, int n) {
  int i = blockIdx.x * 256 + threadIdx.x;
  if (i < n) out[i] = f2bf(in[i]);
}
__global__ void repack_conv_w_kernel(const float* __restrict__ wbot, ushort* __restrict__ Wrb) {
  int idx = blockIdx.x * 256 + threadIdx.x;
  if (idx >= 512 * 9216) return;
  int co = idx / 9216, r = idx % 9216, tap = r >> 10, ci = r & 1023;
  Wrb[idx] = f2bf(wbot[((size_t)co * 1024 + ci) * 9 + tap]);
}

// ---------------------------------------------------------------------------
extern "C" void kernel_launch(void* const* d_in, const int* in_sizes, int n_in,
                              void* d_out, int out_size, void* d_ws, size_t ws_size,
                              hipStream_t stream) {
  const float* x     = (const float*)d_in[0];
  const float* proxy = (const float*)d_in[1];
  const float* wq1   = (const float*)d_in[2];
  const float* bnq1  = (const float*)d_in[3];
  const float* wq2   = (const float*)d_in[4];
  const float* bnq2  = (const float*)d_in[5];
  const float* wk1   = (const float*)d_in[6];
  const float* bnk1  = (const float*)d_in[7];
  const float* wk2   = (const float*)d_in[8];
  const float* bnk2  = (const float*)d_in[9];
  const float* wv    = (const float*)d_in[10];
  const float* bnv   = (const float*)d_in[11];
  const float* wout  = (const float*)d_in[12];
  const float* bnout = (const float*)d_in[13];
  const float* wbot  = (const float*)d_in[14];
  const float* bnbot = (const float*)d_in[15];
  float* out = (float*)d_out;

  const int B = 2, C = 512, CK = 256, KC = 19;
  char* ws = (char*)d_ws;
  const size_t catBytes = (size_t)B * PADROWS * 1024 * 2;  // 137,379,840
  ushort* cat  = (ushort*)ws;
  ushort* bufA = (ushort*)(ws + 137379840);                // q1T, later ctxT (32 MiB)
  ushort* bufB = (ushort*)(ws + 137379840 + 33554432);     // qT (32 MiB)
  ushort* Wrb  = (ushort*)(ws + 204488704);                // 9 MiB
  ushort* wq1b = (ushort*)(ws + 213925888);
  ushort* wq2b = (ushort*)(ws + 214188032);
  ushort* woutb= (ushort*)(ws + 214319104);
  float*  k1   = (float*)(ws + 214581248);
  float*  k2   = k1 + (size_t)B * CK * KC;
  float*  vv   = k2 + (size_t)B * CK * KC;

  // zero padded cat (borders must be 0 every launch; ws is re-poisoned)
  hipMemsetAsync(cat, 0, catBytes, stream);

  // weight conversions
  convert_w_kernel<<<(CK * C + 255) / 256, 256, 0, stream>>>(wq1, wq1b, CK * C);
  convert_w_kernel<<<(CK * CK + 255) / 256, 256, 0, stream>>>(wq2, wq2b, CK * CK);
  convert_w_kernel<<<(C * CK + 255) / 256, 256, 0, stream>>>(wout, woutb, C * CK);
  repack_conv_w_kernel<<<(512 * 9216 + 255) / 256, 256, 0, stream>>>(wbot, Wrb);

  // k/v path (tiny, fp32)
  small_gemm_kernel<<<dim3(CK, B), 64, 0, stream>>>(wk1, proxy, bnk1, k1, CK, C, KC);
  small_gemm_kernel<<<dim3(CK, B), 64, 0, stream>>>(wk2, k1, bnk2, k2, CK, CK, KC);
  small_gemm_kernel<<<dim3(CK, B), 64, 0, stream>>>(wv, proxy, bnv, vv, CK, C, KC);

  // x -> cat_pad channels 512..1023 (bf16, transposed)
  transpose_x_kernel<<<dim3(NPIX / 64, 8, B), 256, 0, stream>>>(x, cat);

  const long padStride = (long)PADROWS * 1024;
  const long nckStride = (long)NPIX * 256;

  // q path: wq1 reads x-part of cat (padded rows, ci offset 512)
  mfma_gemm<1, 0><<<dim3(NPIX / 128, 2, B), 256, 0, stream>>>(
      wq1b, cat, bnq1, bufA, 256, 512, 1024, 512, padStride, 256, nckStride);
  // wq2: plain rows
  mfma_gemm<0, 0><<<dim3(NPIX / 128, 2, B), 256, 0, stream>>>(
      wq2b, bufA, bnq2, bufB, 256, 256, 256, 0, nckStride, 256, nckStride);

  // attention: qT -> ctxT (reuse bufA)
  attention_kernel<<<dim3(NPIX / 256, B), 256, 0, stream>>>(bufB, k2, vv, bufA);

  // wout: ctxT -> cat_pad channels 0..511 (padded rows out)
  mfma_gemm<0, 1><<<dim3(NPIX / 128, 4, B), 256, 0, stream>>>(
      woutb, bufA, bnout, cat, 512, 256, 256, 0, nckStride, 1024, padStride);

  // conv3x3: implicit GEMM over cat_pad, fp32 out + BN + ReLU
  mfma_gemm<2, 2><<<dim3(NPIX / 128, 4, B), 256, 0, stream>>>(
      Wrb, cat, bnbot, out, 512, 9216, 1024, 0, padStride, 0, (long)512 * NPIX);
}

// Round 4
// 1942.037 us; speedup vs baseline: 5.8522x; 1.0276x over previous
//
#include <hip/hip_runtime.h>
#include <cstdint>

#define EPS 1e-5f
#define PADW 258          // W+2
#define PADROWS 33540     // (H+2)*(W+2) = 130*258
#define NPIX 32768        // H*W per batch

typedef __attribute__((ext_vector_type(8))) short bf16x8;
typedef __attribute__((ext_vector_type(4))) float f32x4;

__device__ __forceinline__ ushort f2bf(float f) {
  union { float f; uint32_t u; } v; v.f = f;
  uint32_t r = v.u + 0x7fffu + ((v.u >> 16) & 1u);  // round-to-nearest-even
  return (ushort)(r >> 16);
}
__device__ __forceinline__ float bf2f(ushort h) {
  union { uint32_t u; float f; } v; v.u = ((uint32_t)h) << 16;
  return v.f;
}
__device__ __forceinline__ void gload_lds16(const void* g, void* lds) {
  __builtin_amdgcn_global_load_lds((__attribute__((address_space(1))) void*)g,
                                   (__attribute__((address_space(3))) void*)lds,
                                   16, 0, 0);
}

// ---------------------------------------------------------------------------
// Unified MFMA GEMM (used for the three 1x1 convs) — unchanged from round 3.
// ---------------------------------------------------------------------------
template <int BMODE, int OMODE>
__global__ __launch_bounds__(256) void mfma_gemm(
    const ushort* __restrict__ A, const ushort* __restrict__ B,
    const float* __restrict__ bn, void* __restrict__ OutV,
    int M, int K, int pitchB, int ciB, long strideB, int pitchO, long strideO) {
  const int lane = threadIdx.x & 63;
  const int wave = threadIdx.x >> 6;
  const int wm = (wave & 1) * 64;
  const int wn = (wave >> 1) * 64;
  const int m0 = blockIdx.y * 128;
  const int n0 = blockIdx.x * 128;
  const int z  = blockIdx.z;
  B += (size_t)z * strideB;

  const int h = n0 >> 8, w0 = n0 & 255;
  long prowB;
  if (BMODE == 0) prowB = n0;
  else            prowB = (long)(h + 1) * PADW + (w0 + 1);

  __shared__ __align__(16) ushort Asl[4 * 128 * 8];
  __shared__ __align__(16) ushort Bsl[4 * 128 * 8];

  f32x4 acc[4][4];
#pragma unroll
  for (int mt = 0; mt < 4; ++mt)
#pragma unroll
    for (int nt = 0; nt < 4; ++nt) acc[mt][nt] = (f32x4){0.f, 0.f, 0.f, 0.f};

  for (int k0 = 0; k0 < K; k0 += 32) {
#pragma unroll
    for (int i = 0; i < 2; ++i) {
      int s = wave * 2 + i;
      int c = s * 64 + lane;
      int mm = c & 127, ks = c >> 7;
      gload_lds16(A + (size_t)(m0 + mm) * K + (k0 + ks * 8), Asl + s * 512);
    }
    long rowb; int cib;
    if (BMODE == 2) {
      int tap = k0 >> 10;
      int dy = tap / 3 - 1, dx = tap % 3 - 1;
      rowb = prowB + dy * PADW + dx;
      cib  = k0 & 1023;
    } else {
      rowb = prowB;
      cib  = ciB + k0;
    }
#pragma unroll
    for (int i = 0; i < 2; ++i) {
      int s = wave * 2 + i;
      int c = s * 64 + lane;
      int nn = c & 127, ks = c >> 7;
      gload_lds16(B + (size_t)(rowb + nn) * pitchB + cib + ks * 8, Bsl + s * 512);
    }
    __syncthreads();
    bf16x8 af[4], bfr[4];
#pragma unroll
    for (int t = 0; t < 4; ++t) {
      af[t]  = *(const bf16x8*)(Asl + (((lane >> 4) * 128) + wm + t * 16 + (lane & 15)) * 8);
      bfr[t] = *(const bf16x8*)(Bsl + (((lane >> 4) * 128) + wn + t * 16 + (lane & 15)) * 8);
    }
#pragma unroll
    for (int mt = 0; mt < 4; ++mt)
#pragma unroll
      for (int nt = 0; nt < 4; ++nt)
        acc[mt][nt] = __builtin_amdgcn_mfma_f32_16x16x32_bf16(af[mt], bfr[nt], acc[mt][nt], 0, 0, 0);
    __syncthreads();
  }

  const int q4 = lane >> 4, col = lane & 15;
  float scv[16], bov[16];
#pragma unroll
  for (int mt = 0; mt < 4; ++mt)
#pragma unroll
    for (int r = 0; r < 4; ++r) {
      int m = m0 + wm + mt * 16 + q4 * 4 + r;
      float s = bn[m] * rsqrtf(bn[3 * M + m] + EPS);
      scv[mt * 4 + r] = s;
      bov[mt * 4 + r] = bn[M + m] - bn[2 * M + m] * s;
    }
  if (OMODE == 2) {
    float* Outf = (float*)OutV + (size_t)z * strideO;
#pragma unroll
    for (int mt = 0; mt < 4; ++mt)
#pragma unroll
      for (int r = 0; r < 4; ++r) {
        int m = m0 + wm + mt * 16 + q4 * 4 + r;
        float* rowp = Outf + (size_t)m * NPIX + n0 + wn;
#pragma unroll
        for (int nt = 0; nt < 4; ++nt)
          rowp[nt * 16 + col] = fmaxf(acc[mt][nt][r] * scv[mt * 4 + r] + bov[mt * 4 + r], 0.f);
      }
  } else {
    ushort* Outh = (ushort*)OutV + (size_t)z * strideO;
    long prowO = (OMODE == 0) ? (long)n0 : ((long)(h + 1) * PADW + (w0 + 1));
#pragma unroll
    for (int nt = 0; nt < 4; ++nt) {
      long row = prowO + wn + nt * 16 + col;
      ushort* p = Outh + (size_t)row * pitchO + m0 + wm;
#pragma unroll
      for (int mt = 0; mt < 4; ++mt) {
        ushort4 pk;
        pk.x = f2bf(fmaxf(acc[mt][nt][0] * scv[mt * 4 + 0] + bov[mt * 4 + 0], 0.f));
        pk.y = f2bf(fmaxf(acc[mt][nt][1] * scv[mt * 4 + 1] + bov[mt * 4 + 1], 0.f));
        pk.z = f2bf(fmaxf(acc[mt][nt][2] * scv[mt * 4 + 2] + bov[mt * 4 + 2], 0.f));
        pk.w = f2bf(fmaxf(acc[mt][nt][3] * scv[mt * 4 + 3] + bov[mt * 4 + 3], 0.f));
        *(ushort4*)(p + mt * 16 + q4 * 4) = pk;
      }
    }
  }
}

// ---------------------------------------------------------------------------
// Conv3x3 as halo-LDS implicit GEMM.
// K-loop: 32 iterations over ci-chunks of 32. Per iter:
//   - stage B halo: [octet o(0..3)][row r(0..2)][px p(0..135, use 0..129)][8ci]
//     packed 16B chunks, contiguous in (o,r,p) order -> global_load_lds OK.
//   - 9 taps x (4 A-frag global loads from L2-hot weights + 4 ds_read_b128 +
//     16 MFMA) per wave = 144 MFMA between barriers.
// Grid x = n_tile*4 + m_tile so each XCD holds one m-tile's weights in L2.
// ---------------------------------------------------------------------------
#define HALO_OSTR 408   // 3*136 chunks per octet
#define HALO_RSTR 136   // px dim (only 0..129 used)
__global__ __launch_bounds__(256, 2) void conv3x3_mfma(
    const ushort* __restrict__ Wr, const ushort* __restrict__ cat,
    const float* __restrict__ bn, float* __restrict__ out) {
  const int tid  = threadIdx.x;
  const int lane = tid & 63;
  const int wave = tid >> 6;
  const int wm = (wave & 1) * 64;
  const int wn = (wave >> 1) * 64;
  const int m0 = (blockIdx.x & 3) * 128;
  const int n0 = (blockIdx.x >> 2) * 128;
  const int z  = blockIdx.z;
  const int h = n0 >> 8, w0 = n0 & 255;
  const long prow0 = (long)(h + 1) * PADW + (w0 + 1);
  const ushort* Bz = cat + (size_t)z * PADROWS * 1024;

  __shared__ __align__(16) ushort halo[1792 * 8];  // 28672 B (1632 chunks + pad)

  f32x4 acc[4][4];
#pragma unroll
  for (int mt = 0; mt < 4; ++mt)
#pragma unroll
    for (int nt = 0; nt < 4; ++nt) acc[mt][nt] = (f32x4){0.f, 0.f, 0.f, 0.f};

  // Precompute per-thread halo staging source offsets (ci-independent).
  long offs[7];
#pragma unroll
  for (int s = 0; s < 7; ++s) {
    int c = s * 256 + tid;
    if (c > 1631) c = 1631;
    int o = c / HALO_OSTR;
    int rem = c - o * HALO_OSTR;
    int r = rem / HALO_RSTR;
    int p = rem - r * HALO_RSTR;
    if (p > 129) p = 129;
    offs[s] = ((prow0 + (long)(r - 1) * PADW + (p - 1)) << 10) + o * 8;
  }

  // Per-lane A base: row = m0+wm+(lane&15), k-octet = lane>>4.
  const ushort* Abase = Wr + (size_t)(m0 + wm + (lane & 15)) * 9216 + (lane >> 4) * 8;
  const int hlane = (lane >> 4) * HALO_OSTR + wn + (lane & 15);

  for (int ci0 = 0; ci0 < 1024; ci0 += 32) {
#pragma unroll
    for (int s = 0; s < 7; ++s)
      gload_lds16(Bz + offs[s] + ci0, halo + ((size_t)s * 256 + wave * 64) * 8);
    __syncthreads();

    for (int t = 0; t < 9; ++t) {
      const ushort* At = Abase + t * 1024 + ci0;
      bf16x8 af[4];
#pragma unroll
      for (int mt = 0; mt < 4; ++mt)
        af[mt] = *(const bf16x8*)(At + (size_t)mt * 16 * 9216);
      const int hb = hlane + (t / 3) * HALO_RSTR + (t % 3);
#pragma unroll
      for (int nt = 0; nt < 4; ++nt) {
        bf16x8 bfr = *(const bf16x8*)(halo + (size_t)(hb + nt * 16) * 8);
#pragma unroll
        for (int mt = 0; mt < 4; ++mt)
          acc[mt][nt] = __builtin_amdgcn_mfma_f32_16x16x32_bf16(af[mt], bfr, acc[mt][nt], 0, 0, 0);
      }
    }
    __syncthreads();
  }

  // Epilogue: BN + ReLU, fp32 NCHW out.
  const int q4 = lane >> 4, col = lane & 15;
  float* Outf = out + (size_t)z * 512 * NPIX;
#pragma unroll
  for (int mt = 0; mt < 4; ++mt)
#pragma unroll
    for (int r = 0; r < 4; ++r) {
      int m = m0 + wm + mt * 16 + q4 * 4 + r;
      float s  = bn[m] * rsqrtf(bn[3 * 512 + m] + EPS);
      float bo = bn[512 + m] - bn[2 * 512 + m] * s;
      float* rowp = Outf + (size_t)m * NPIX + n0 + wn;
#pragma unroll
      for (int nt = 0; nt < 4; ++nt)
        rowp[nt * 16 + col] = fmaxf(acc[mt][nt][r] * s + bo, 0.f);
    }
}

// ---------------------------------------------------------------------------
// Tiny GEMM for the k/v path (fp32, negligible cost)
// ---------------------------------------------------------------------------
__global__ __launch_bounds__(64) void small_gemm_kernel(
    const float* __restrict__ Wm, const float* __restrict__ X,
    const float* __restrict__ bn, float* __restrict__ Y,
    int CO, int CI, int KC) {
  int co = blockIdx.x, b = blockIdx.y, kc = threadIdx.x;
  if (kc >= KC) return;
  const float* Xb = X + (size_t)b * CI * KC;
  float acc = 0.f;
  for (int c = 0; c < CI; ++c) acc += Wm[(size_t)co * CI + c] * Xb[(size_t)c * KC + kc];
  float s  = bn[co] * rsqrtf(bn[3 * CO + co] + EPS);
  float bs = bn[CO + co] - bn[2 * CO + co] * s;
  Y[((size_t)b * CO + co) * KC + kc] = fmaxf(acc * s + bs, 0.f);
}

// ---------------------------------------------------------------------------
// Attention: qT/ctxT in [pixel][256ch] bf16; k/v fp32 staged in LDS.
// ---------------------------------------------------------------------------
__global__ __launch_bounds__(256) void attention_kernel(
    const ushort* __restrict__ qT, const float* __restrict__ Kp,
    const float* __restrict__ Vp, ushort* __restrict__ ctxT) {
  int b = blockIdx.y;
  int pix = blockIdx.x * 256 + threadIdx.x;
  __shared__ float ks[256][19], vs[256][19];
  for (int idx = threadIdx.x; idx < 256 * 19; idx += 256) {
    int c = idx / 19, kk = idx % 19;
    ks[c][kk] = Kp[((size_t)b * 256 + c) * 19 + kk];
    vs[c][kk] = Vp[((size_t)b * 256 + c) * 19 + kk];
  }
  __syncthreads();

  const ushort* qrow = qT + ((size_t)b * NPIX + pix) * 256;
  float sim[19];
#pragma unroll
  for (int kk = 0; kk < 19; ++kk) sim[kk] = 0.f;
  for (int c0 = 0; c0 < 256; c0 += 8) {
    uint4 raw = *(const uint4*)(qrow + c0);
    float qf[8] = {bf2f((ushort)(raw.x & 0xffff)), bf2f((ushort)(raw.x >> 16)),
                   bf2f((ushort)(raw.y & 0xffff)), bf2f((ushort)(raw.y >> 16)),
                   bf2f((ushort)(raw.z & 0xffff)), bf2f((ushort)(raw.z >> 16)),
                   bf2f((ushort)(raw.w & 0xffff)), bf2f((ushort)(raw.w >> 16))};
#pragma unroll
    for (int j = 0; j < 8; ++j)
#pragma unroll
      for (int kk = 0; kk < 19; ++kk) sim[kk] += qf[j] * ks[c0 + j][kk];
  }
  const float scale = 0.0625f;
  float mx = -1e30f;
#pragma unroll
  for (int kk = 0; kk < 19; ++kk) { sim[kk] *= scale; mx = fmaxf(mx, sim[kk]); }
  float denom = 0.f;
#pragma unroll
  for (int kk = 0; kk < 19; ++kk) { sim[kk] = __expf(sim[kk] - mx); denom += sim[kk]; }
  float inv = 1.f / denom;
#pragma unroll
  for (int kk = 0; kk < 19; ++kk) sim[kk] *= inv;

  ushort* crow = ctxT + ((size_t)b * NPIX + pix) * 256;
  for (int c0 = 0; c0 < 256; c0 += 8) {
    uint32_t o[4];
#pragma unroll
    for (int j = 0; j < 4; ++j) {
      float v0 = 0.f, v1 = 0.f;
#pragma unroll
      for (int kk = 0; kk < 19; ++kk) {
        v0 += sim[kk] * vs[c0 + j * 2][kk];
        v1 += sim[kk] * vs[c0 + j * 2 + 1][kk];
      }
      o[j] = (uint32_t)f2bf(v0) | ((uint32_t)f2bf(v1) << 16);
    }
    *(uint4*)(crow + c0) = make_uint4(o[0], o[1], o[2], o[3]);
  }
}

// ---------------------------------------------------------------------------
// Transpose x (fp32 [b][512][HW]) into cat_pad (bf16 [b][p][1024], ch 512..1023)
// ---------------------------------------------------------------------------
__global__ __launch_bounds__(256) void transpose_x_kernel(
    const float* __restrict__ x, ushort* __restrict__ cat) {
  int b = blockIdx.z, ci0 = blockIdx.y * 64, n0 = blockIdx.x * 64;
  __shared__ float t[64][65];
  const float* xb = x + ((size_t)b * 512 + ci0) * NPIX + n0;
  for (int i = 0; i < 16; ++i) {
    int idx = i * 256 + threadIdx.x;
    int c = idx >> 6, w = idx & 63;
    t[c][w] = xb[(size_t)c * NPIX + w];
  }
  __syncthreads();
  int h = n0 >> 8, w0 = n0 & 255;
  size_t pbase = ((size_t)b * PADROWS + (size_t)(h + 1) * PADW + (w0 + 1)) * 1024 + 512 + ci0;
  for (int i = 0; i < 16; ++i) {
    int idx = i * 256 + threadIdx.x;
    int n = idx >> 6, c = idx & 63;
    cat[pbase + (size_t)n * 1024 + c] = f2bf(t[c][n]);
  }
}

// ---------------------------------------------------------------------------
// Weight conversions
// ---------------------------------------------------------------------------
__global__ void convert_w_kernel(const float* __restrict__ in, ushort* __restrict__ out, int n) {
  int i = blockIdx.x * 256 + threadIdx.x;
  if (i < n) out[i] = f2bf(in[i]);
}
__global__ void repack_conv_w_kernel(const float* __restrict__ wbot, ushort* __restrict__ Wrb) {
  int idx = blockIdx.x * 256 + threadIdx.x;
  if (idx >= 512 * 9216) return;
  int co = idx / 9216, r = idx % 9216, tap = r >> 10, ci = r & 1023;
  Wrb[idx] = f2bf(wbot[((size_t)co * 1024 + ci) * 9 + tap]);
}

// ---------------------------------------------------------------------------
extern "C" void kernel_launch(void* const* d_in, const int* in_sizes, int n_in,
                              void* d_out, int out_size, void* d_ws, size_t ws_size,
                              hipStream_t stream) {
  const float* x     = (const float*)d_in[0];
  const float* proxy = (const float*)d_in[1];
  const float* wq1   = (const float*)d_in[2];
  const float* bnq1  = (const float*)d_in[3];
  const float* wq2   = (const float*)d_in[4];
  const float* bnq2  = (const float*)d_in[5];
  const float* wk1   = (const float*)d_in[6];
  const float* bnk1  = (const float*)d_in[7];
  const float* wk2   = (const float*)d_in[8];
  const float* bnk2  = (const float*)d_in[9];
  const float* wv    = (const float*)d_in[10];
  const float* bnv   = (const float*)d_in[11];
  const float* wout  = (const float*)d_in[12];
  const float* bnout = (const float*)d_in[13];
  const float* wbot  = (const float*)d_in[14];
  const float* bnbot = (const float*)d_in[15];
  float* out = (float*)d_out;

  const int B = 2, C = 512, CK = 256, KC = 19;
  char* ws = (char*)d_ws;
  const size_t catBytes = (size_t)B * PADROWS * 1024 * 2;  // 137,379,840
  ushort* cat  = (ushort*)ws;
  ushort* bufA = (ushort*)(ws + 137379840);                // q1T, later ctxT (32 MiB)
  ushort* bufB = (ushort*)(ws + 137379840 + 33554432);     // qT (32 MiB)
  ushort* Wrb  = (ushort*)(ws + 204488704);                // 9 MiB
  ushort* wq1b = (ushort*)(ws + 213925888);
  ushort* wq2b = (ushort*)(ws + 214188032);
  ushort* woutb= (ushort*)(ws + 214319104);
  float*  k1   = (float*)(ws + 214581248);
  float*  k2   = k1 + (size_t)B * CK * KC;
  float*  vv   = k2 + (size_t)B * CK * KC;

  hipMemsetAsync(cat, 0, catBytes, stream);

  convert_w_kernel<<<(CK * C + 255) / 256, 256, 0, stream>>>(wq1, wq1b, CK * C);
  convert_w_kernel<<<(CK * CK + 255) / 256, 256, 0, stream>>>(wq2, wq2b, CK * CK);
  convert_w_kernel<<<(C * CK + 255) / 256, 256, 0, stream>>>(wout, woutb, C * CK);
  repack_conv_w_kernel<<<(512 * 9216 + 255) / 256, 256, 0, stream>>>(wbot, Wrb);

  small_gemm_kernel<<<dim3(CK, B), 64, 0, stream>>>(wk1, proxy, bnk1, k1, CK, C, KC);
  small_gemm_kernel<<<dim3(CK, B), 64, 0, stream>>>(wk2, k1, bnk2, k2, CK, CK, KC);
  small_gemm_kernel<<<dim3(CK, B), 64, 0, stream>>>(wv, proxy, bnv, vv, CK, C, KC);

  transpose_x_kernel<<<dim3(NPIX / 64, 8, B), 256, 0, stream>>>(x, cat);

  const long padStride = (long)PADROWS * 1024;
  const long nckStride = (long)NPIX * 256;

  mfma_gemm<1, 0><<<dim3(NPIX / 128, 2, B), 256, 0, stream>>>(
      wq1b, cat, bnq1, bufA, 256, 512, 1024, 512, padStride, 256, nckStride);
  mfma_gemm<0, 0><<<dim3(NPIX / 128, 2, B), 256, 0, stream>>>(
      wq2b, bufA, bnq2, bufB, 256, 256, 256, 0, nckStride, 256, nckStride);

  attention_kernel<<<dim3(NPIX / 256, B), 256, 0, stream>>>(bufB, k2, vv, bufA);

  mfma_gemm<0, 1><<<dim3(NPIX / 128, 4, B), 256, 0, stream>>>(
      woutb, bufA, bnout, cat, 512, 256, 256, 0, nckStride, 1024, padStride);

  // conv3x3: halo-LDS implicit GEMM; grid.x = n_tile*4 + m_tile (XCD swizzle)
  conv3x3_mfma<<<dim3((NPIX / 128) * 4, 1, B), 256, 0, stream>>>(Wrb, cat, bnbot, out);
}